// Round 12
// baseline (119.917 us; speedup 1.0000x reference)
//
#include <hip/hip_runtime.h>
#include <math.h>

// Deepmd angular descriptor, f32 in / f32 out. B=8, N=4096, M=96, OUT_W=384.
//
// R12 vs R11 (~32 us): explicit 2-pair-ahead software pipeline of the three
// global input streams (neighbors/mask/offsets). R11 relied on the compiler
// to hoist loads across the unrolled NITER loop; at launch_bounds(1024,8)
// (64-VGPR cap) it didn't (R10 used 32 VGPRs), so each pair ate a full HBM
// latency. Now 3 pair-bundles (~10 VGPRs each) are in flight: prologue loads
// pairs 0,1; iteration `it` issues pair it+2's loads first, then processes
// pair it. Epilogue stays R11's: in-register ballot/popc stable rank (ranks
// of nonzero items are distinct), register merge, one coalesced b128+b64 row
// store. LDS = 64 KB float4 position table only; one __syncthreads total.
#define M_NB   96
#define OUT_W  384
#define NATOM  4096
#define WPB    16
#define NITER  4

struct Pst {               // per-lane stream bundle for one pair
    int    jA, jB;
    float  mkA, mkB;
    float3 oA, oB;
};

__device__ __forceinline__ void load_pst(Pst& s,
    const int* __restrict__ nb, const float* __restrict__ mk,
    const float* __restrict__ of, long q, int lane, bool low)
{
    const long eA = q * M_NB + lane;
    s.jA  = nb[eA];
    s.mkA = mk[eA];
    s.oA  = *(const float3*)(of + eA * 3);
    if (low) {
        const long eB = eA + 64;
        s.jB  = nb[eB];
        s.mkB = mk[eB];
        s.oB  = *(const float3*)(of + eB * 3);
    } else {
        s.jB = 0; s.mkB = 0.f; s.oB = make_float3(0.f, 0.f, 0.f);
    }
}

// fold one item (row floats [base,base+3)) into this lane's output slots:
// float4 owns [4*lane,4*lane+4), float2 owns [256+2*lane,256+2*lane+2)
__device__ __forceinline__ void merge3(float4& a4, float2& a2, int base,
                                       float v0, float v1, float v2, int lane)
{
    const int f4lo = 4 * lane;
    const int f2lo = 256 + 2 * lane;
    const float v[3] = {v0, v1, v2};
    #pragma unroll
    for (int t = 0; t < 3; ++t) {
        const int idx = base + t;
        if      (idx == f4lo)     a4.x = v[t];
        else if (idx == f4lo + 1) a4.y = v[t];
        else if (idx == f4lo + 2) a4.z = v[t];
        else if (idx == f4lo + 3) a4.w = v[t];
        else if (idx == f2lo)     a2.x = v[t];
        else if (idx == f2lo + 1) a2.y = v[t];
    }
}

__global__ __launch_bounds__(64 * WPB, 8) void deepmd_angular_kernel(
    const float* __restrict__ positions,  // [B,N,3]
    const float* __restrict__ cell,       // [B,3,3]
    const float* __restrict__ offsets,    // [B,N,M,3]
    const float* __restrict__ mask,       // [B,N,M]
    const int*   __restrict__ neighbors,  // [B,N,M]
    float*       __restrict__ out,        // [B,N,OUT_W]
    int N)
{
    __shared__ float4 pos4_s[NATOM];        // 64 KB padded position table

    const int tid  = threadIdx.x;
    const int wv   = tid >> 6;
    const int lane = tid & 63;
    const bool low = lane < 32;

    const int p0 = blockIdx.x * (WPB * NITER);   // first pair of block
    const int b  = p0 / N;                       // uniform (64 | N)

    // ---- stage batch positions -> LDS (padded to 16 B/atom) ----
    {
        const float* pb_ = positions + (size_t)b * N * 3;
        for (int a = tid; a < NATOM; a += 64 * WPB) {
            const float3 v = *(const float3*)(pb_ + 3 * a);
            pos4_s[a] = make_float4(v.x, v.y, v.z, 0.f);
        }
    }
    __syncthreads();                             // only barrier in the kernel

    const float* cb = cell + (size_t)b * 9;      // uniform -> scalar loads
    const float c00 = cb[0], c01 = cb[1], c02 = cb[2];
    const float c10 = cb[3], c11 = cb[4], c12 = cb[5];
    const float c20 = cb[6], c21 = cb[7], c22 = cb[8];

    const long qb = (long)(p0 + wv * NITER);     // this wave's first pair

    // ---- pipeline prologue: pairs 0 and 1 in flight ----
    Pst s0, s1;
    load_pst(s0, neighbors, mask, offsets, qb + 0, lane, low);
    load_pst(s1, neighbors, mask, offsets, qb + 1, lane, low);

    #pragma unroll
    for (int it = 0; it < NITER; ++it) {
        // issue pair it+2's stream loads before touching pair it's data
        Pst nx;
        if (it + 2 < NITER)
            load_pst(nx, neighbors, mask, offsets, qb + it + 2, lane, low);

        const int q  = (int)qb + it;
        const int nn = q - b * N;                // local atom index

        const float4 pi  = pos4_s[nn];           // uniform b128 broadcast
        const float4 pjA = pos4_s[s0.jA];        // 1 x ds_read_b128 gather

        const float dxA = pjA.x - pi.x + s0.oA.x * c00 + s0.oA.y * c10 + s0.oA.z * c20;
        const float dyA = pjA.y - pi.y + s0.oA.x * c01 + s0.oA.y * c11 + s0.oA.z * c21;
        const float dzA = pjA.z - pi.z + s0.oA.x * c02 + s0.oA.y * c12 + s0.oA.z * c22;
        const float dA  = sqrtf(dxA * dxA + dyA * dyA + dzA * dzA + 1e-12f);
        float cutA = 0.f;
        if (s0.mkA != 0.f && dA < 6.f)
            cutA = 0.5f * (__cosf(dA * 0.52359877559829887f) + 1.f) / dA;

        float dxB = 0.f, dyB = 0.f, dzB = 0.f, cutB = 0.f;
        if (low) {
            const float4 pjB = pos4_s[s0.jB];
            dxB = pjB.x - pi.x + s0.oB.x * c00 + s0.oB.y * c10 + s0.oB.z * c20;
            dyB = pjB.y - pi.y + s0.oB.x * c01 + s0.oB.y * c11 + s0.oB.z * c21;
            dzB = pjB.z - pi.z + s0.oB.x * c02 + s0.oB.y * c12 + s0.oB.z * c22;
            const float dB = sqrtf(dxB * dxB + dyB * dyB + dzB * dzB + 1e-12f);
            if (s0.mkB != 0.f && dB < 6.f)
                cutB = 0.5f * (__cosf(dB * 0.52359877559829887f) + 1.f) / dB;
        }

        const float w0A = cutA * dxA, w1A = cutA * dyA, w2A = cutA * dzA;
        const float w0B = cutB * dxB, w1B = cutB * dyB, w2B = cutB * dzB;

        // ---- in-register stable rank + merge (no LDS, no fences) ----
        // rank(m) = #{k: cut_k > cut_m} + #{k<m: cut_k == cut_m}
        float4 a4 = make_float4(0.f, 0.f, 0.f, 0.f);
        float2 a2 = make_float2(0.f, 0.f);

        unsigned long long t = __ballot(cutA != 0.f);
        while (t) {
            const int s = (int)__builtin_ctzll(t); t &= t - 1;   // item m = s
            const float c = __shfl(cutA, s);
            const unsigned long long gtA = __ballot(cutA > c);
            const unsigned long long gtB = __ballot(cutB > c);
            const unsigned long long eqA = __ballot(cutA == c);
            const int rank = __popcll(gtA) + __popcll(gtB)
                           + __popcll(eqA & ((1ull << s) - 1ull));
            merge3(a4, a2, 3 * rank,
                   __shfl(w0A, s), __shfl(w1A, s), __shfl(w2A, s), lane);
        }
        t = __ballot(cutB != 0.f);
        while (t) {
            const int s = (int)__builtin_ctzll(t); t &= t - 1;   // item m = 64+s
            const float c = __shfl(cutB, s);
            const unsigned long long gtA = __ballot(cutA > c);
            const unsigned long long gtB = __ballot(cutB > c);
            const unsigned long long eqA = __ballot(cutA == c);  // all k<64 < m
            const unsigned long long eqB = __ballot(cutB == c);
            const int rank = __popcll(gtA) + __popcll(gtB) + __popcll(eqA)
                           + __popcll(eqB & ((1ull << s) - 1ull));
            merge3(a4, a2, 3 * rank,
                   __shfl(w0B, s), __shfl(w1B, s), __shfl(w2B, s), lane);
        }

        // ---- single full-wave coalesced row store (1536 B) ----
        float* rowp = out + (size_t)q * OUT_W;
        ((float4*)rowp)[lane] = a4;              // floats   0..255
        ((float2*)(rowp + 256))[lane] = a2;      // floats 256..383

        // rotate pipeline
        s0 = s1; s1 = nx;
    }
}

extern "C" void kernel_launch(void* const* d_in, const int* in_sizes, int n_in,
                              void* d_out, int out_size, void* d_ws, size_t ws_size,
                              hipStream_t stream) {
    const float* positions = (const float*)d_in[0];
    const float* cell      = (const float*)d_in[1];
    const float* offsets   = (const float*)d_in[2];
    const float* mask      = (const float*)d_in[3];
    const int*   neighbors = (const int*)d_in[4];
    float*       out       = (float*)d_out;

    const int BN = in_sizes[0] / 3;        // B*N = 32768
    const int B  = in_sizes[1] / 9;        // 8
    const int N  = BN / B;                 // 4096

    dim3 block(64 * WPB, 1, 1);            // 1024 threads = 16 waves
    dim3 grid(BN / (WPB * NITER), 1, 1);   // 512 blocks = 2/CU resident
    deepmd_angular_kernel<<<grid, block, 0, stream>>>(
        positions, cell, offsets, mask, neighbors, out, N);
}

// Round 13
// 118.285 us; speedup vs baseline: 1.0138x; 1.0138x over previous
//
#include <hip/hip_runtime.h>
#include <math.h>

// Deepmd angular descriptor, f32 in / f32 out. B=8, N=4096, M=96, OUT_W=384.
//
// R13 vs R12 (~32 us, neutral): R12 prefetched the global streams but issued
// the LDS position gather in-iteration, right before use -- leaving a ~300
// cyc serial chain (ds_read_b128 random gather ~120-200 cyc + sqrt/cos +
// ballots) per pair. Now a 3-stage pipeline: iteration `it` issues streams
// for it+2, LDS gathers for it+1 (from streams landed last iteration), and
// computes/stores pair `it` from gathers issued one iteration ago. Epilogue
// unchanged from R11: in-register ballot/popc stable rank, register merge,
// one coalesced b128+b64 row store. LDS = 64 KB float4 position table.
#define M_NB   96
#define OUT_W  384
#define NATOM  4096
#define WPB    16
#define NITER  4

struct Pst {               // per-lane stream bundle for one pair
    int    jA, jB;
    float  mkA, mkB;
    float3 oA, oB;
};

struct Gth {               // per-lane gather bundle for one pair
    float4 pi, pjA, pjB;
};

__device__ __forceinline__ void load_pst(Pst& s,
    const int* __restrict__ nb, const float* __restrict__ mk,
    const float* __restrict__ of, long q, int lane, bool low)
{
    const long eA = q * M_NB + lane;
    s.jA  = nb[eA];
    s.mkA = mk[eA];
    s.oA  = *(const float3*)(of + eA * 3);
    if (low) {
        const long eB = eA + 64;
        s.jB  = nb[eB];
        s.mkB = mk[eB];
        s.oB  = *(const float3*)(of + eB * 3);
    } else {
        s.jB = 0; s.mkB = 0.f; s.oB = make_float3(0.f, 0.f, 0.f);
    }
}

// fold one item (row floats [base,base+3)) into this lane's output slots:
// float4 owns [4*lane,4*lane+4), float2 owns [256+2*lane,256+2*lane+2)
__device__ __forceinline__ void merge3(float4& a4, float2& a2, int base,
                                       float v0, float v1, float v2, int lane)
{
    const int f4lo = 4 * lane;
    const int f2lo = 256 + 2 * lane;
    const float v[3] = {v0, v1, v2};
    #pragma unroll
    for (int t = 0; t < 3; ++t) {
        const int idx = base + t;
        if      (idx == f4lo)     a4.x = v[t];
        else if (idx == f4lo + 1) a4.y = v[t];
        else if (idx == f4lo + 2) a4.z = v[t];
        else if (idx == f4lo + 3) a4.w = v[t];
        else if (idx == f2lo)     a2.x = v[t];
        else if (idx == f2lo + 1) a2.y = v[t];
    }
}

__global__ __launch_bounds__(64 * WPB, 8) void deepmd_angular_kernel(
    const float* __restrict__ positions,  // [B,N,3]
    const float* __restrict__ cell,       // [B,3,3]
    const float* __restrict__ offsets,    // [B,N,M,3]
    const float* __restrict__ mask,       // [B,N,M]
    const int*   __restrict__ neighbors,  // [B,N,M]
    float*       __restrict__ out,        // [B,N,OUT_W]
    int N)
{
    __shared__ float4 pos4_s[NATOM];        // 64 KB padded position table

    const int tid  = threadIdx.x;
    const int wv   = tid >> 6;
    const int lane = tid & 63;
    const bool low = lane < 32;

    const int p0 = blockIdx.x * (WPB * NITER);   // first pair of block
    const int b  = p0 / N;                       // uniform (64 | N)

    // ---- stage batch positions -> LDS (padded to 16 B/atom) ----
    {
        const float* pb_ = positions + (size_t)b * N * 3;
        for (int a = tid; a < NATOM; a += 64 * WPB) {
            const float3 v = *(const float3*)(pb_ + 3 * a);
            pos4_s[a] = make_float4(v.x, v.y, v.z, 0.f);
        }
    }
    __syncthreads();                             // only barrier in the kernel

    const float* cb = cell + (size_t)b * 9;      // uniform -> scalar loads
    const float c00 = cb[0], c01 = cb[1], c02 = cb[2];
    const float c10 = cb[3], c11 = cb[4], c12 = cb[5];
    const float c20 = cb[6], c21 = cb[7], c22 = cb[8];

    const long qb = (long)(p0 + wv * NITER);     // this wave's first pair

    // ---- pipeline prologue ----
    Pst s0, s1;
    load_pst(s0, neighbors, mask, offsets, qb + 0, lane, low);
    load_pst(s1, neighbors, mask, offsets, qb + 1, lane, low);
    Gth g0;
    g0.pi  = pos4_s[(int)(qb + 0) - b * N];
    g0.pjA = pos4_s[s0.jA];
    g0.pjB = pos4_s[s0.jB];

    #pragma unroll
    for (int it = 0; it < NITER; ++it) {
        // stage 1: streams for pair it+2
        Pst nxs;
        if (it + 2 < NITER)
            load_pst(nxs, neighbors, mask, offsets, qb + it + 2, lane, low);
        // stage 2: LDS gathers for pair it+1 (streams already landed)
        Gth g1;
        if (it + 1 < NITER) {
            g1.pi  = pos4_s[(int)(qb + it + 1) - b * N];
            g1.pjA = pos4_s[s1.jA];
            g1.pjB = pos4_s[s1.jB];
        }

        // stage 3: compute pair it from g0/s0
        const int q = (int)qb + it;

        const float dxA = g0.pjA.x - g0.pi.x + s0.oA.x * c00 + s0.oA.y * c10 + s0.oA.z * c20;
        const float dyA = g0.pjA.y - g0.pi.y + s0.oA.x * c01 + s0.oA.y * c11 + s0.oA.z * c21;
        const float dzA = g0.pjA.z - g0.pi.z + s0.oA.x * c02 + s0.oA.y * c12 + s0.oA.z * c22;
        const float dA  = sqrtf(dxA * dxA + dyA * dyA + dzA * dzA + 1e-12f);
        float cutA = 0.f;
        if (s0.mkA != 0.f && dA < 6.f)
            cutA = 0.5f * (__cosf(dA * 0.52359877559829887f) + 1.f) / dA;

        float dxB = 0.f, dyB = 0.f, dzB = 0.f, cutB = 0.f;
        if (low) {
            dxB = g0.pjB.x - g0.pi.x + s0.oB.x * c00 + s0.oB.y * c10 + s0.oB.z * c20;
            dyB = g0.pjB.y - g0.pi.y + s0.oB.x * c01 + s0.oB.y * c11 + s0.oB.z * c21;
            dzB = g0.pjB.z - g0.pi.z + s0.oB.x * c02 + s0.oB.y * c12 + s0.oB.z * c22;
            const float dB = sqrtf(dxB * dxB + dyB * dyB + dzB * dzB + 1e-12f);
            if (s0.mkB != 0.f && dB < 6.f)
                cutB = 0.5f * (__cosf(dB * 0.52359877559829887f) + 1.f) / dB;
        }

        const float w0A = cutA * dxA, w1A = cutA * dyA, w2A = cutA * dzA;
        const float w0B = cutB * dxB, w1B = cutB * dyB, w2B = cutB * dzB;

        // ---- in-register stable rank + merge (no LDS, no fences) ----
        // rank(m) = #{k: cut_k > cut_m} + #{k<m: cut_k == cut_m}
        float4 a4 = make_float4(0.f, 0.f, 0.f, 0.f);
        float2 a2 = make_float2(0.f, 0.f);

        unsigned long long t = __ballot(cutA != 0.f);
        while (t) {
            const int s = (int)__builtin_ctzll(t); t &= t - 1;   // item m = s
            const float c = __shfl(cutA, s);
            const unsigned long long gtA = __ballot(cutA > c);
            const unsigned long long gtB = __ballot(cutB > c);
            const unsigned long long eqA = __ballot(cutA == c);
            const int rank = __popcll(gtA) + __popcll(gtB)
                           + __popcll(eqA & ((1ull << s) - 1ull));
            merge3(a4, a2, 3 * rank,
                   __shfl(w0A, s), __shfl(w1A, s), __shfl(w2A, s), lane);
        }
        t = __ballot(cutB != 0.f);
        while (t) {
            const int s = (int)__builtin_ctzll(t); t &= t - 1;   // item m = 64+s
            const float c = __shfl(cutB, s);
            const unsigned long long gtA = __ballot(cutA > c);
            const unsigned long long gtB = __ballot(cutB > c);
            const unsigned long long eqA = __ballot(cutA == c);  // all k<64 < m
            const unsigned long long eqB = __ballot(cutB == c);
            const int rank = __popcll(gtA) + __popcll(gtB) + __popcll(eqA)
                           + __popcll(eqB & ((1ull << s) - 1ull));
            merge3(a4, a2, 3 * rank,
                   __shfl(w0B, s), __shfl(w1B, s), __shfl(w2B, s), lane);
        }

        // ---- single full-wave coalesced row store (1536 B) ----
        float* rowp = out + (size_t)q * OUT_W;
        ((float4*)rowp)[lane] = a4;              // floats   0..255
        ((float2*)(rowp + 256))[lane] = a2;      // floats 256..383

        // rotate pipeline
        s0 = s1; s1 = nxs; g0 = g1;
    }
}

extern "C" void kernel_launch(void* const* d_in, const int* in_sizes, int n_in,
                              void* d_out, int out_size, void* d_ws, size_t ws_size,
                              hipStream_t stream) {
    const float* positions = (const float*)d_in[0];
    const float* cell      = (const float*)d_in[1];
    const float* offsets   = (const float*)d_in[2];
    const float* mask      = (const float*)d_in[3];
    const int*   neighbors = (const int*)d_in[4];
    float*       out       = (float*)d_out;

    const int BN = in_sizes[0] / 3;        // B*N = 32768
    const int B  = in_sizes[1] / 9;        // 8
    const int N  = BN / B;                 // 4096

    dim3 block(64 * WPB, 1, 1);            // 1024 threads = 16 waves
    dim3 grid(BN / (WPB * NITER), 1, 1);   // 512 blocks = 2/CU resident
    deepmd_angular_kernel<<<grid, block, 0, stream>>>(
        positions, cell, offsets, mask, neighbors, out, N);
}